// Round 1
// baseline (502.520 us; speedup 1.0000x reference)
//
#include <hip/hip_runtime.h>
#include <stdint.h>

#define T_ 2048
#define C_ 2048
#define HD 128
#define LDQKV 3072

typedef unsigned short u16;
typedef __attribute__((ext_vector_type(8))) short bf16x8;   // 8 bf16 (4 VGPRs), per guide §3
typedef __attribute__((ext_vector_type(4))) float f32x4;
typedef __attribute__((ext_vector_type(4))) float float4v;
typedef __attribute__((ext_vector_type(4))) u16 u16x4;
typedef __attribute__((ext_vector_type(8))) u16 u16x8;

typedef __attribute__((address_space(3))) void lds_void;
typedef const __attribute__((address_space(1))) void gbl_void;

// global -> LDS direct DMA, 16B/lane. LDS dest is wave-uniform base + lane*16.
__device__ __forceinline__ void gload_lds16(const void* g, void* l) {
  __builtin_amdgcn_global_load_lds((gbl_void*)(uintptr_t)g,
                                   (lds_void*)(uint32_t)(uintptr_t)l, 16, 0, 0);
}

__device__ __forceinline__ u16 f2bf(float f) {
  union { float f; uint32_t u; } v; v.f = f;
  uint32_t r = v.u + 0x7FFFu + ((v.u >> 16) & 1u);
  return (u16)(r >> 16);
}
__device__ __forceinline__ float bf2f(u16 h) {
  union { uint32_t u; float f; } v; v.u = ((uint32_t)h) << 16;
  return v.f;
}

// ---------- conversions ----------
__global__ __launch_bounds__(256) void k_conv_x(const float* __restrict__ x, u16* __restrict__ o) {
  size_t idx = (size_t)blockIdx.x * 256 + threadIdx.x;   // over float4 units
  float4v xv = *(const float4v*)(x + idx * 4);
  u16x4 r;
#pragma unroll
  for (int e = 0; e < 4; ++e) r[e] = f2bf(xv[e]);
  *(u16x4*)(o + idx * 4) = r;
}

// wt[n][k] = W[k][n] for combined [Wq | Wk | Wv], n in [0,3072), k in [0,2048)
__global__ __launch_bounds__(256) void k_wt_qkv(const float* __restrict__ Wq, const float* __restrict__ Wk,
                                                const float* __restrict__ Wv, u16* __restrict__ wt) {
  int idx = blockIdx.x * 256 + threadIdx.x;
  int n = idx >> 11, k = idx & 2047;
  float v;
  if (n < 2048)      v = Wq[(size_t)k * 2048 + n];
  else if (n < 2560) v = Wk[(size_t)k * 512 + (n - 2048)];
  else               v = Wv[(size_t)k * 512 + (n - 2560)];
  wt[idx] = f2bf(v);
}

__global__ __launch_bounds__(256) void k_wo_t(const float* __restrict__ Wo, u16* __restrict__ wt) {
  int idx = blockIdx.x * 256 + threadIdx.x;
  int n = idx >> 11, k = idx & 2047;
  wt[idx] = f2bf(Wo[(size_t)k * 2048 + n]);
}

// cos/sin table: cst[(t*64+d)*2 + {0,1}] = cos/sin(t * 10000^(-d/64))
__global__ __launch_bounds__(256) void k_cs(float* __restrict__ cst) {
  int idx = blockIdx.x * 256 + threadIdx.x;   // 131072
  int t = idx >> 6, d = idx & 63;
  float inv = expf(-(float)d * (1.0f / 64.0f) * 9.2103403719761836f); // ln(10000)
  float f = (float)t * inv;
  float s, c;
  sincosf(f, &s, &c);
  cst[idx * 2] = c;
  cst[idx * 2 + 1] = s;
}

// RoPE in place on q (cols 0..2047) and k (cols 2048..2559) of qkv[8192][3072]
__global__ __launch_bounds__(256) void k_rope(u16* __restrict__ qkv, const float* __restrict__ cst) {
  int idx = blockIdx.x * 256 + threadIdx.x;   // 8192*20*64 = 10,485,760
  int token = idx / 1280;
  int rem = idx - token * 1280;
  int hd = rem >> 6, d = rem & 63;
  int col = (hd < 16) ? (hd * 128 + d) : (2048 + (hd - 16) * 128 + d);
  size_t base = (size_t)token * LDQKV + col;
  int t = token & (T_ - 1);
  float c = cst[(t * 64 + d) * 2];
  float s = cst[(t * 64 + d) * 2 + 1];
  float x1 = bf2f(qkv[base]);
  float x2 = bf2f(qkv[base + 64]);
  qkv[base]      = f2bf(x1 * c - x2 * s);
  qkv[base + 64] = f2bf(x1 * s + x2 * c);
}

// ---------- GEMM: C[M][N] = A[M][K] * Bt[N][K]^T  (m97 structure: 128x128 tile, BK=64) ----------
template<int OUTF32>
__global__ __launch_bounds__(256) void k_gemm(const u16* __restrict__ A, const u16* __restrict__ Bt,
                                              void* __restrict__ Cout, int M, int N, int K) {
  __shared__ __attribute__((aligned(16))) u16 As[128 * 64];
  __shared__ __attribute__((aligned(16))) u16 Bs[128 * 64];
  const int tid = threadIdx.x, lane = tid & 63, w = tid >> 6;
  const int wm = w >> 1, wn = w & 1;
  const int m0 = blockIdx.y * 128, n0 = blockIdx.x * 128;
  const int l15 = lane & 15, lhi = lane >> 4;

  f32x4 acc[4][4];
#pragma unroll
  for (int i = 0; i < 4; ++i)
#pragma unroll
    for (int j = 0; j < 4; ++j) acc[i][j] = (f32x4){0.f, 0.f, 0.f, 0.f};

  for (int k0 = 0; k0 < K; k0 += 64) {
    // stage A,B tiles: 1024 16B-chunks each; chunk = it*256 + tid; row=chunk>>3, kc=chunk&7
#pragma unroll
    for (int it = 0; it < 4; ++it) {
      int chunk = it * 256 + tid;
      int row = chunk >> 3, kc = chunk & 7;
      gload_lds16(A + (size_t)(m0 + row) * K + k0 + kc * 8, &As[(it * 256 + w * 64) * 8]);
    }
#pragma unroll
    for (int it = 0; it < 4; ++it) {
      int chunk = it * 256 + tid;
      int row = chunk >> 3, kc = chunk & 7;
      gload_lds16(Bt + (size_t)(n0 + row) * K + k0 + kc * 8, &Bs[(it * 256 + w * 64) * 8]);
    }
    __syncthreads();   // compiler drains vmcnt(0) here -> staged data valid
#pragma unroll
    for (int ks = 0; ks < 2; ++ks) {
      bf16x8 af[4], bb[4];
#pragma unroll
      for (int mt = 0; mt < 4; ++mt)
        af[mt] = *(const bf16x8*)&As[(wm * 64 + mt * 16 + l15) * 64 + ks * 32 + lhi * 8];
#pragma unroll
      for (int nt = 0; nt < 4; ++nt)
        bb[nt] = *(const bf16x8*)&Bs[(wn * 64 + nt * 16 + l15) * 64 + ks * 32 + lhi * 8];
#pragma unroll
      for (int mt = 0; mt < 4; ++mt)
#pragma unroll
        for (int nt = 0; nt < 4; ++nt)
          acc[mt][nt] = __builtin_amdgcn_mfma_f32_16x16x32_bf16(af[mt], bb[nt], acc[mt][nt], 0, 0, 0);
    }
    __syncthreads();
  }
  // epilogue: C/D layout col=lane&15, row=(lane>>4)*4+r (guide §3, m89/m91-verified)
#pragma unroll
  for (int mt = 0; mt < 4; ++mt) {
#pragma unroll
    for (int nt = 0; nt < 4; ++nt) {
      int col = n0 + wn * 64 + nt * 16 + l15;
#pragma unroll
      for (int r = 0; r < 4; ++r) {
        int row = m0 + wm * 64 + mt * 16 + lhi * 4 + r;
        float v = acc[mt][nt][r];
        if (OUTF32) ((float*)Cout)[(size_t)row * N + col] = v;
        else        ((u16*)Cout)[(size_t)row * N + col] = f2bf(v);
      }
    }
  }
}

// ---------- windowed flash attention ----------
// block: (b, h, 64-query tile); 4 waves x 16 q-rows; K/V tiles of 64 keys, <=5 per block
__global__ __launch_bounds__(256) void k_attn(const u16* __restrict__ qkv, u16* __restrict__ y) {
  const int bid = blockIdx.x;
  const int qt = bid & 31, h = (bid >> 5) & 15, b = bid >> 9;
  const int i0 = qt * 64;
  const size_t tb = (size_t)b * T_ * LDQKV;
  const u16* qb = qkv + tb + h * HD;
  const u16* kb = qkv + tb + 2048 + (h >> 2) * HD;
  const u16* vb = kb + 512;
  __shared__ __attribute__((aligned(16))) u16 Qs[64 * 128];
  __shared__ __attribute__((aligned(16))) u16 Ks[64 * 128];
  __shared__ __attribute__((aligned(16))) u16 Vt[128 * 64];      // V transposed: Vt[d][j]
  __shared__ __attribute__((aligned(16))) u16 Ps[4][16 * 64];    // per-wave P tile
  const int tid = threadIdx.x, lane = tid & 63, w = tid >> 6;
  const int l15 = lane & 15, lhi = lane >> 4;

  // stage Q tile [64][128]
#pragma unroll
  for (int it = 0; it < 4; ++it) {
    int chunk = it * 256 + tid, row = chunk >> 4, kc = chunk & 15;
    gload_lds16(qb + (size_t)(i0 + row) * LDQKV + kc * 8, &Qs[(it * 256 + w * 64) * 8]);
  }
  __syncthreads();
  // hoist Q fragments (wave w owns q rows w*16..w*16+15; A-frag row = lane&15)
  bf16x8 qf[4];
#pragma unroll
  for (int ks = 0; ks < 4; ++ks)
    qf[ks] = *(const bf16x8*)&Qs[(w * 16 + l15) * 128 + ks * 32 + lhi * 8];

  f32x4 o[8];
#pragma unroll
  for (int dt = 0; dt < 8; ++dt) o[dt] = (f32x4){0.f, 0.f, 0.f, 0.f};
  float mrun[4], lrun[4];
#pragma unroll
  for (int r = 0; r < 4; ++r) { mrun[r] = -1e30f; lrun[r] = 0.f; }

  const int jb0 = (i0 >= 256) ? (i0 - 256) : 0;
  for (int jb = jb0; jb <= i0; jb += 64) {
    // stage K tile [64][128] via direct DMA
#pragma unroll
    for (int it = 0; it < 4; ++it) {
      int chunk = it * 256 + tid, row = chunk >> 4, kc = chunk & 15;
      gload_lds16(kb + (size_t)(jb + row) * LDQKV + kc * 8, &Ks[(it * 256 + w * 64) * 8]);
    }
    // stage V transposed via register staging
#pragma unroll
    for (int it = 0; it < 4; ++it) {
      int chunk = it * 256 + tid, row = chunk >> 4, dc = chunk & 15;
      u16x8 vv = *(const u16x8*)(vb + (size_t)(jb + row) * LDQKV + dc * 8);
#pragma unroll
      for (int e = 0; e < 8; ++e) Vt[(dc * 8 + e) * 64 + row] = vv[e];
    }
    __syncthreads();

    // S = Q K^T  (D: row=q=(lhi*4+r), col=key=l15, per 16-key tile t)
    f32x4 s[4];
#pragma unroll
    for (int t = 0; t < 4; ++t) {
      s[t] = (f32x4){0.f, 0.f, 0.f, 0.f};
#pragma unroll
      for (int ks = 0; ks < 4; ++ks) {
        bf16x8 kf = *(const bf16x8*)&Ks[(t * 16 + l15) * 128 + ks * 32 + lhi * 8];
        s[t] = __builtin_amdgcn_mfma_f32_16x16x32_bf16(qf[ks], kf, s[t], 0, 0, 0);
      }
    }

    // mask + scale + online softmax (wave-parallel: 16-lane shfl_xor reduce)
    const int irow0 = i0 + w * 16 + lhi * 4;
    float rmax[4];
#pragma unroll
    for (int r = 0; r < 4; ++r) rmax[r] = -1e30f;
#pragma unroll
    for (int t = 0; t < 4; ++t) {
      int j = jb + t * 16 + l15;
#pragma unroll
      for (int r = 0; r < 4; ++r) {
        int i = irow0 + r;
        float sv = s[t][r] * 0.08838834764831845f;   // 1/sqrt(128)
        sv = (j <= i && j + 256 >= i) ? sv : -1e30f;
        s[t][r] = sv;
        rmax[r] = fmaxf(rmax[r], sv);
      }
    }
#pragma unroll
    for (int r = 0; r < 4; ++r) {
#pragma unroll
      for (int off = 1; off < 16; off <<= 1)
        rmax[r] = fmaxf(rmax[r], __shfl_xor(rmax[r], off));
    }
    float sf[4], psum[4];
#pragma unroll
    for (int r = 0; r < 4; ++r) {
      float mn = fmaxf(mrun[r], rmax[r]);
      sf[r] = __expf(mrun[r] - mn);
      mrun[r] = mn;
      psum[r] = 0.f;
    }
#pragma unroll
    for (int t = 0; t < 4; ++t) {
#pragma unroll
      for (int r = 0; r < 4; ++r) {
        float p = __expf(s[t][r] - mrun[r]);   // masked -> exp(-1e30-m) = 0
        psum[r] += p;
        Ps[w][(lhi * 4 + r) * 64 + t * 16 + l15] = f2bf(p);
      }
    }
#pragma unroll
    for (int r = 0; r < 4; ++r) {
#pragma unroll
      for (int off = 1; off < 16; off <<= 1)
        psum[r] += __shfl_xor(psum[r], off);
      lrun[r] = lrun[r] * sf[r] + psum[r];
    }
#pragma unroll
    for (int dt = 0; dt < 8; ++dt)
#pragma unroll
      for (int r = 0; r < 4; ++r)
        o[dt][r] = o[dt][r] * sf[r];
    __syncthreads();   // P visible (cross-lane), Vt/Ks already synced

    // O += P V   (A-frag from Ps: row=q=l15, k=key; B-frag from Vt: col=d=l15)
    bf16x8 pf[2];
#pragma unroll
    for (int ks2 = 0; ks2 < 2; ++ks2)
      pf[ks2] = *(const bf16x8*)&Ps[w][l15 * 64 + ks2 * 32 + lhi * 8];
#pragma unroll
    for (int dt = 0; dt < 8; ++dt) {
#pragma unroll
      for (int ks2 = 0; ks2 < 2; ++ks2) {
        bf16x8 vf = *(const bf16x8*)&Vt[(dt * 16 + l15) * 64 + ks2 * 32 + lhi * 8];
        o[dt] = __builtin_amdgcn_mfma_f32_16x16x32_bf16(pf[ks2], vf, o[dt], 0, 0, 0);
      }
    }
    __syncthreads();   // all reads of Ks/Vt done before next stage
  }

  // epilogue: y[b][i][h*128 + d] = O/l
#pragma unroll
  for (int dt = 0; dt < 8; ++dt) {
#pragma unroll
    for (int r = 0; r < 4; ++r) {
      int i = i0 + w * 16 + lhi * 4 + r;
      float v = o[dt][r] / lrun[r];
      y[((size_t)b * T_ + i) * C_ + h * HD + dt * 16 + l15] = f2bf(v);
    }
  }
}

extern "C" void kernel_launch(void* const* d_in, const int* in_sizes, int n_in,
                              void* d_out, int out_size, void* d_ws, size_t ws_size,
                              hipStream_t stream) {
  const float* x  = (const float*)d_in[0];
  const float* Wq = (const float*)d_in[1];
  const float* Wk = (const float*)d_in[2];
  const float* Wv = (const float*)d_in[3];
  const float* Wo = (const float*)d_in[4];
  char* ws = (char*)d_ws;
  // workspace layout (~106 MB total)
  u16* x_bf   = (u16*)(ws);                 // 33,554,432 B  (reused as y after GEMM1)
  u16* wt_qkv = (u16*)(ws + 33554432);      // 12,582,912 B
  u16* wo_t   = (u16*)(ws + 46137344);      //  8,388,608 B
  u16* qkv    = (u16*)(ws + 54525952);      // 50,331,648 B
  float* cst  = (float*)(ws + 104857600);   //  1,048,576 B
  u16* ybuf = x_bf;

  k_conv_x <<<16384, 256, 0, stream>>>(x, x_bf);                 // 4,194,304 float4
  k_wt_qkv <<<24576, 256, 0, stream>>>(Wq, Wk, Wv, wt_qkv);      // 6,291,456
  k_wo_t   <<<16384, 256, 0, stream>>>(Wo, wo_t);                // 4,194,304
  k_cs     <<<512,   256, 0, stream>>>(cst);                     // 131,072

  dim3 g1(24, 64);   // N=3072/128, M=8192/128
  k_gemm<0><<<g1, 256, 0, stream>>>(x_bf, wt_qkv, (void*)qkv, 8192, 3072, 2048);

  k_rope   <<<40960, 256, 0, stream>>>(qkv, cst);                // 10,485,760
  k_attn   <<<2048,  256, 0, stream>>>(qkv, ybuf);               // (b,h,qtile)

  dim3 g2(16, 64);   // N=2048/128
  k_gemm<1><<<g2, 256, 0, stream>>>(ybuf, wo_t, d_out, 8192, 2048, 2048);
}

// Round 2
// 406.996 us; speedup vs baseline: 1.2347x; 1.2347x over previous
//
#include <hip/hip_runtime.h>
#include <stdint.h>

#define T_ 2048
#define C_ 2048
#define HD 128
#define LDQKV 3072

typedef unsigned short u16;
typedef __attribute__((ext_vector_type(8))) short bf16x8;   // 8 bf16 (4 VGPRs)
typedef __attribute__((ext_vector_type(4))) float f32x4;
typedef __attribute__((ext_vector_type(4))) float float4v;
typedef __attribute__((ext_vector_type(4))) u16 u16x4;
typedef __attribute__((ext_vector_type(8))) u16 u16x8;

typedef __attribute__((address_space(3))) void lds_void;
typedef const __attribute__((address_space(1))) void gbl_void;

// global -> LDS direct DMA, 16B/lane. LDS dest is wave-uniform base + lane*16.
__device__ __forceinline__ void gload_lds16(const void* g, void* l) {
  __builtin_amdgcn_global_load_lds((gbl_void*)(uintptr_t)g,
                                   (lds_void*)(uint32_t)(uintptr_t)l, 16, 0, 0);
}

__device__ __forceinline__ u16 f2bf(float f) {
  union { float f; uint32_t u; } v; v.f = f;
  uint32_t r = v.u + 0x7FFFu + ((v.u >> 16) & 1u);
  return (u16)(r >> 16);
}
__device__ __forceinline__ float bf2f(u16 h) {
  union { uint32_t u; float f; } v; v.u = ((uint32_t)h) << 16;
  return v.f;
}

// ---------- conversions ----------
__global__ __launch_bounds__(256) void k_conv_x(const float* __restrict__ x, u16* __restrict__ o) {
  size_t idx = (size_t)blockIdx.x * 256 + threadIdx.x;   // over float4 units
  float4v xv = *(const float4v*)(x + idx * 4);
  u16x4 r;
#pragma unroll
  for (int e = 0; e < 4; ++e) r[e] = f2bf(xv[e]);
  *(u16x4*)(o + idx * 4) = r;
}

// wt[n][k] = W[k][n] for combined [Wq | Wk | Wv], n in [0,3072), k in [0,2048)
__global__ __launch_bounds__(256) void k_wt_qkv(const float* __restrict__ Wq, const float* __restrict__ Wk,
                                                const float* __restrict__ Wv, u16* __restrict__ wt) {
  int idx = blockIdx.x * 256 + threadIdx.x;
  int n = idx >> 11, k = idx & 2047;
  float v;
  if (n < 2048)      v = Wq[(size_t)k * 2048 + n];
  else if (n < 2560) v = Wk[(size_t)k * 512 + (n - 2048)];
  else               v = Wv[(size_t)k * 512 + (n - 2560)];
  wt[idx] = f2bf(v);
}

__global__ __launch_bounds__(256) void k_wo_t(const float* __restrict__ Wo, u16* __restrict__ wt) {
  int idx = blockIdx.x * 256 + threadIdx.x;
  int n = idx >> 11, k = idx & 2047;
  wt[idx] = f2bf(Wo[(size_t)k * 2048 + n]);
}

// cos/sin table: cst[(t*64+d)*2 + {0,1}] = cos/sin(t * 10000^(-d/64))
__global__ __launch_bounds__(256) void k_cs(float* __restrict__ cst) {
  int idx = blockIdx.x * 256 + threadIdx.x;   // 131072
  int t = idx >> 6, d = idx & 63;
  float inv = expf(-(float)d * (1.0f / 64.0f) * 9.2103403719761836f); // ln(10000)
  float f = (float)t * inv;
  float s, c;
  sincosf(f, &s, &c);
  cst[idx * 2] = c;
  cst[idx * 2 + 1] = s;
}

// RoPE in place, vectorized x8. Also folds 1/sqrt(HD) into q (heads 0..15).
// thread: (token, hd20, oct) ; hd<16 -> q head, else k head (hd-16)
__global__ __launch_bounds__(256) void k_rope(u16* __restrict__ qkv, const float* __restrict__ cst) {
  int idx = blockIdx.x * 256 + threadIdx.x;   // 8192*20*8 = 1,310,720
  int token = idx / 160;
  int rem = idx - token * 160;
  int hd = rem >> 3, oct = rem & 7;
  int col = ((hd < 16) ? hd * 128 : 2048 + (hd - 16) * 128) + oct * 8;
  size_t base = (size_t)token * LDQKV + col;
  int t = token & (T_ - 1);
  float sc = (hd < 16) ? 0.08838834764831845f : 1.0f;   // 1/sqrt(128) folded into q
  u16x8 a = *(const u16x8*)(qkv + base);
  u16x8 b2 = *(const u16x8*)(qkv + base + 64);
  const float* cp = cst + (size_t)(t * 64 + oct * 8) * 2;
  u16x8 ra, rb;
#pragma unroll
  for (int e = 0; e < 8; ++e) {
    float c = cp[e * 2], s = cp[e * 2 + 1];
    float x1 = bf2f(a[e]), x2 = bf2f(b2[e]);
    ra[e] = f2bf((x1 * c - x2 * s) * sc);
    rb[e] = f2bf((x1 * s + x2 * c) * sc);
  }
  *(u16x8*)(qkv + base) = ra;
  *(u16x8*)(qkv + base + 64) = rb;
}

// ---------- GEMM: C[M][N] = A[M][K] * Bt[N][K]^T  (m97 structure: 128x128 tile, BK=64) ----------
template<int OUTF32>
__global__ __launch_bounds__(256) void k_gemm(const u16* __restrict__ A, const u16* __restrict__ Bt,
                                              void* __restrict__ Cout, int M, int N, int K) {
  __shared__ __attribute__((aligned(16))) u16 As[128 * 64];
  __shared__ __attribute__((aligned(16))) u16 Bs[128 * 64];
  const int tid = threadIdx.x, lane = tid & 63, w = tid >> 6;
  const int wm = w >> 1, wn = w & 1;
  const int m0 = blockIdx.y * 128, n0 = blockIdx.x * 128;
  const int l15 = lane & 15, lhi = lane >> 4;

  f32x4 acc[4][4];
#pragma unroll
  for (int i = 0; i < 4; ++i)
#pragma unroll
    for (int j = 0; j < 4; ++j) acc[i][j] = (f32x4){0.f, 0.f, 0.f, 0.f};

  for (int k0 = 0; k0 < K; k0 += 64) {
#pragma unroll
    for (int it = 0; it < 4; ++it) {
      int chunk = it * 256 + tid;
      int row = chunk >> 3, kc = chunk & 7;
      gload_lds16(A + (size_t)(m0 + row) * K + k0 + kc * 8, &As[(it * 256 + w * 64) * 8]);
    }
#pragma unroll
    for (int it = 0; it < 4; ++it) {
      int chunk = it * 256 + tid;
      int row = chunk >> 3, kc = chunk & 7;
      gload_lds16(Bt + (size_t)(n0 + row) * K + k0 + kc * 8, &Bs[(it * 256 + w * 64) * 8]);
    }
    __syncthreads();
#pragma unroll
    for (int ks = 0; ks < 2; ++ks) {
      bf16x8 af[4], bb[4];
#pragma unroll
      for (int mt = 0; mt < 4; ++mt)
        af[mt] = *(const bf16x8*)&As[(wm * 64 + mt * 16 + l15) * 64 + ks * 32 + lhi * 8];
#pragma unroll
      for (int nt = 0; nt < 4; ++nt)
        bb[nt] = *(const bf16x8*)&Bs[(wn * 64 + nt * 16 + l15) * 64 + ks * 32 + lhi * 8];
#pragma unroll
      for (int mt = 0; mt < 4; ++mt)
#pragma unroll
        for (int nt = 0; nt < 4; ++nt)
          acc[mt][nt] = __builtin_amdgcn_mfma_f32_16x16x32_bf16(af[mt], bb[nt], acc[mt][nt], 0, 0, 0);
    }
    __syncthreads();
  }
#pragma unroll
  for (int mt = 0; mt < 4; ++mt) {
#pragma unroll
    for (int nt = 0; nt < 4; ++nt) {
      int col = n0 + wn * 64 + nt * 16 + l15;
#pragma unroll
      for (int r = 0; r < 4; ++r) {
        int row = m0 + wm * 64 + mt * 16 + lhi * 4 + r;
        float v = acc[mt][nt][r];
        if (OUTF32) ((float*)Cout)[(size_t)row * N + col] = v;
        else        ((u16*)Cout)[(size_t)row * N + col] = f2bf(v);
      }
    }
  }
}

// ---------- windowed flash attention (bank-conflict-free LDS) ----------
// block: (b, h, 64-query tile); 4 waves x 16 q-rows; K/V tiles of 64 keys, <=5 per block
// LDS 40KB (Qs aliases Ks after hoist) -> 4 blocks/CU.
// Swizzles (all XOR involutions, rule #21 both-sides):
//   Qs/Ks [64][128]: 16B-chunk kc' = kc ^ (row&7)
//   Vt    [128][64]: j-block    j' = j  ^ ((((d>>3)^(d&7))&7)<<3)  (write lanes vary d>>3, read lanes vary d&15)
//   Ps    [16][64] : k          k' = k  ^ ((q&7)<<3)
__global__ __launch_bounds__(256) void k_attn(const u16* __restrict__ qkv, u16* __restrict__ y) {
  const int bid = blockIdx.x;
  const int qt = bid & 31, h = (bid >> 5) & 15, b = bid >> 9;
  const int i0 = qt * 64;
  const size_t tb = (size_t)b * T_ * LDQKV;
  const u16* qb = qkv + tb + h * HD;
  const u16* kb = qkv + tb + 2048 + (h >> 2) * HD;
  const u16* vb = kb + 512;
  __shared__ __attribute__((aligned(16))) u16 smem[20480];   // 40 KB
  u16* Ks = smem;              // 64*128 = 8192 u16 (16KB), chunk-swizzled
  u16* Vt = smem + 8192;       // 128*64 = 8192 u16 (16KB), j-swizzled
  u16* Psw = smem + 16384;     // 4 waves * 16*64 = 4096 u16 (8KB), k-swizzled
  u16* Qs = smem;              // aliases Ks region during prologue
  const int tid = threadIdx.x, lane = tid & 63, w = tid >> 6;
  const int l15 = lane & 15, lhi = lane >> 4;
  u16* Ps = Psw + w * 1024;

  // stage Q tile [64][128], pre-swizzled source (LDS dest linear)
#pragma unroll
  for (int it = 0; it < 4; ++it) {
    int c = it * 256 + tid, row = c >> 4, kc = (c & 15) ^ (row & 7);
    gload_lds16(qb + (size_t)(i0 + row) * LDQKV + kc * 8, &Qs[(it * 256 + w * 64) * 8]);
  }
  __syncthreads();
  // hoist Q fragments (wave w owns q rows w*16..w*16+15; A-frag row = lane&15)
  bf16x8 qf[4];
#pragma unroll
  for (int ks = 0; ks < 4; ++ks) {
    int row = w * 16 + l15;
    int kc = (ks * 4 + lhi) ^ (row & 7);
    qf[ks] = *(const bf16x8*)&Qs[(row * 16 + kc) * 8];
  }
  __syncthreads();   // Qs region about to be overwritten by Ks staging

  f32x4 o[8];
#pragma unroll
  for (int dt = 0; dt < 8; ++dt) o[dt] = (f32x4){0.f, 0.f, 0.f, 0.f};
  float mrun[4], lrun[4];
#pragma unroll
  for (int r = 0; r < 4; ++r) { mrun[r] = -1e30f; lrun[r] = 0.f; }

  const int jb0 = (i0 >= 256) ? (i0 - 256) : 0;
  for (int jb = jb0; jb <= i0; jb += 64) {
    // stage K tile [64][128] via DMA, pre-swizzled source
#pragma unroll
    for (int it = 0; it < 4; ++it) {
      int c = it * 256 + tid, row = c >> 4, kc = (c & 15) ^ (row & 7);
      gload_lds16(kb + (size_t)(jb + row) * LDQKV + kc * 8, &Ks[(it * 256 + w * 64) * 8]);
    }
    // stage V transposed via register staging, dual-varying swizzle
#pragma unroll
    for (int it = 0; it < 4; ++it) {
      int chunk = it * 256 + tid, row = chunk >> 4, dc = chunk & 15;   // row=j, dc=d-block
      u16x8 vv = *(const u16x8*)(vb + (size_t)(jb + row) * LDQKV + dc * 8);
#pragma unroll
      for (int e = 0; e < 8; ++e) {
        int d = dc * 8 + e;
        int s = (dc ^ e) & 7;
        Vt[d * 64 + (row ^ (s << 3))] = vv[e];
      }
    }
    __syncthreads();

    // S = Q K^T  (D: row=q=(lhi*4+r), col=key=l15, per 16-key tile t); scale pre-folded into q
    f32x4 s[4];
#pragma unroll
    for (int t = 0; t < 4; ++t) {
      s[t] = (f32x4){0.f, 0.f, 0.f, 0.f};
#pragma unroll
      for (int ks = 0; ks < 4; ++ks) {
        int row = t * 16 + l15;
        int kc = (ks * 4 + lhi) ^ (row & 7);
        bf16x8 kf = *(const bf16x8*)&Ks[(row * 16 + kc) * 8];
        s[t] = __builtin_amdgcn_mfma_f32_16x16x32_bf16(qf[ks], kf, s[t], 0, 0, 0);
      }
    }

    // mask + online softmax (wave-parallel: 16-lane shfl_xor reduce)
    const int irow0 = i0 + w * 16 + lhi * 4;
    float rmax[4];
#pragma unroll
    for (int r = 0; r < 4; ++r) rmax[r] = -1e30f;
#pragma unroll
    for (int t = 0; t < 4; ++t) {
      int j = jb + t * 16 + l15;
#pragma unroll
      for (int r = 0; r < 4; ++r) {
        int i = irow0 + r;
        float sv = s[t][r];
        sv = (j <= i && j + 256 >= i) ? sv : -1e30f;
        s[t][r] = sv;
        rmax[r] = fmaxf(rmax[r], sv);
      }
    }
#pragma unroll
    for (int r = 0; r < 4; ++r) {
#pragma unroll
      for (int off = 1; off < 16; off <<= 1)
        rmax[r] = fmaxf(rmax[r], __shfl_xor(rmax[r], off));
    }
    float sf[4], psum[4];
#pragma unroll
    for (int r = 0; r < 4; ++r) {
      float mn = fmaxf(mrun[r], rmax[r]);
      sf[r] = __expf(mrun[r] - mn);
      mrun[r] = mn;
      psum[r] = 0.f;
    }
#pragma unroll
    for (int t = 0; t < 4; ++t) {
#pragma unroll
      for (int r = 0; r < 4; ++r) {
        float p = __expf(s[t][r] - mrun[r]);   // masked -> 0
        psum[r] += p;
        int q = lhi * 4 + r;
        int k = t * 16 + l15;
        Ps[q * 64 + (k ^ ((q & 7) << 3))] = f2bf(p);
      }
    }
#pragma unroll
    for (int r = 0; r < 4; ++r) {
#pragma unroll
      for (int off = 1; off < 16; off <<= 1)
        psum[r] += __shfl_xor(psum[r], off);
      lrun[r] = lrun[r] * sf[r] + psum[r];
    }
#pragma unroll
    for (int dt = 0; dt < 8; ++dt)
#pragma unroll
      for (int r = 0; r < 4; ++r)
        o[dt][r] = o[dt][r] * sf[r];
    // no barrier: Ps is per-wave; compiler orders ds_write->ds_read via lgkmcnt

    // O += P V   (A-frag from Ps: row=q=l15; B-frag from Vt: col=d)
    bf16x8 pf[2];
#pragma unroll
    for (int ks2 = 0; ks2 < 2; ++ks2)
      pf[ks2] = *(const bf16x8*)&Ps[l15 * 64 + ((ks2 * 32 + lhi * 8) ^ ((l15 & 7) << 3))];
#pragma unroll
    for (int dt = 0; dt < 8; ++dt) {
#pragma unroll
      for (int ks2 = 0; ks2 < 2; ++ks2) {
        int d = dt * 16 + l15;
        int s2 = ((d >> 3) ^ (d & 7)) & 7;
        bf16x8 vf = *(const bf16x8*)&Vt[d * 64 + ((ks2 * 32 + lhi * 8) ^ (s2 << 3))];
        o[dt] = __builtin_amdgcn_mfma_f32_16x16x32_bf16(pf[ks2], vf, o[dt], 0, 0, 0);
      }
    }
    __syncthreads();   // all reads of Ks/Vt done before next stage overwrites
  }

  // epilogue: y[b][i][h*128 + d] = O/l
#pragma unroll
  for (int dt = 0; dt < 8; ++dt) {
#pragma unroll
    for (int r = 0; r < 4; ++r) {
      int i = i0 + w * 16 + lhi * 4 + r;
      float v = o[dt][r] / lrun[r];
      y[((size_t)b * T_ + i) * C_ + h * HD + dt * 16 + l15] = f2bf(v);
    }
  }
}

extern "C" void kernel_launch(void* const* d_in, const int* in_sizes, int n_in,
                              void* d_out, int out_size, void* d_ws, size_t ws_size,
                              hipStream_t stream) {
  const float* x  = (const float*)d_in[0];
  const float* Wq = (const float*)d_in[1];
  const float* Wk = (const float*)d_in[2];
  const float* Wv = (const float*)d_in[3];
  const float* Wo = (const float*)d_in[4];
  char* ws = (char*)d_ws;
  u16* x_bf   = (u16*)(ws);                 // 33,554,432 B  (reused as y after GEMM1)
  u16* wt_qkv = (u16*)(ws + 33554432);      // 12,582,912 B
  u16* wo_t   = (u16*)(ws + 46137344);      //  8,388,608 B
  u16* qkv    = (u16*)(ws + 54525952);      // 50,331,648 B
  float* cst  = (float*)(ws + 104857600);   //  1,048,576 B
  u16* ybuf = x_bf;

  k_conv_x <<<16384, 256, 0, stream>>>(x, x_bf);
  k_wt_qkv <<<24576, 256, 0, stream>>>(Wq, Wk, Wv, wt_qkv);
  k_wo_t   <<<16384, 256, 0, stream>>>(Wo, wo_t);
  k_cs     <<<512,   256, 0, stream>>>(cst);

  dim3 g1(24, 64);   // N=3072/128, M=8192/128
  k_gemm<0><<<g1, 256, 0, stream>>>(x_bf, wt_qkv, (void*)qkv, 8192, 3072, 2048);

  k_rope   <<<5120,  256, 0, stream>>>(qkv, cst);   // 1,310,720 threads, x8 vectorized
  k_attn   <<<2048,  256, 0, stream>>>(qkv, ybuf);

  dim3 g2(16, 64);   // N=2048/128
  k_gemm<1><<<g2, 256, 0, stream>>>(ybuf, wo_t, d_out, 8192, 2048, 2048);
}

// Round 3
// 310.037 us; speedup vs baseline: 1.6208x; 1.3127x over previous
//
#include <hip/hip_runtime.h>
#include <stdint.h>

#define T_ 2048
#define C_ 2048
#define HD 128
#define LDQKV 3072

typedef unsigned short u16;
typedef __attribute__((ext_vector_type(8))) short bf16x8;   // 8 bf16 (4 VGPRs)
typedef __attribute__((ext_vector_type(4))) float f32x4;
typedef __attribute__((ext_vector_type(4))) float float4v;
typedef __attribute__((ext_vector_type(4))) u16 u16x4;
typedef __attribute__((ext_vector_type(8))) u16 u16x8;

typedef __attribute__((address_space(3))) void lds_void;
typedef const __attribute__((address_space(1))) void gbl_void;

__device__ __forceinline__ void gload_lds16(const void* g, void* l) {
  __builtin_amdgcn_global_load_lds((gbl_void*)(uintptr_t)g,
                                   (lds_void*)(uint32_t)(uintptr_t)l, 16, 0, 0);
}

__device__ __forceinline__ u16 f2bf(float f) {
  union { float f; uint32_t u; } v; v.f = f;
  uint32_t r = v.u + 0x7FFFu + ((v.u >> 16) & 1u);
  return (u16)(r >> 16);
}
__device__ __forceinline__ float bf2f(u16 h) {
  union { uint32_t u; float f; } v; v.u = ((uint32_t)h) << 16;
  return v.f;
}

// raw barrier (NOT __syncthreads: that emits s_waitcnt vmcnt(0) and kills the pipeline)
#define BAR() do { asm volatile("" ::: "memory"); __builtin_amdgcn_s_barrier(); asm volatile("" ::: "memory"); } while (0)
#define VMCNT(n) asm volatile("s_waitcnt vmcnt(" #n ")" ::: "memory")
#define LGKM0()  asm volatile("s_waitcnt lgkmcnt(0)" ::: "memory")

// ---------- conversions ----------
__global__ __launch_bounds__(256) void k_conv_x(const float* __restrict__ x, u16* __restrict__ o) {
  size_t idx = (size_t)blockIdx.x * 256 + threadIdx.x;
  float4v xv = *(const float4v*)(x + idx * 4);
  u16x4 r;
#pragma unroll
  for (int e = 0; e < 4; ++e) r[e] = f2bf(xv[e]);
  *(u16x4*)(o + idx * 4) = r;
}

// LDS-tiled transpose+convert: out[n][k] = src[k][n], 64x64 tiles, both sides coalesced
__device__ __forceinline__ void ttile(const float* __restrict__ src, int ldw, int nb,
                                      int k0, int n0out, u16* __restrict__ out, int tid,
                                      float (*Lt)[68]) {
  int kr = tid >> 4, nc = (tid & 15) * 4;
#pragma unroll
  for (int s = 0; s < 4; ++s) {
    float4v v = *(const float4v*)(src + (size_t)(k0 + kr + 16 * s) * ldw + nb + nc);
#pragma unroll
    for (int e = 0; e < 4; ++e) Lt[kr + 16 * s][nc + e] = v[e];
  }
  __syncthreads();
  int nr = tid & 31, kc = (tid >> 5) * 8;
#pragma unroll
  for (int s2 = 0; s2 < 2; ++s2) {
    int n = nr + 32 * s2;
    u16x8 o;
#pragma unroll
    for (int e = 0; e < 8; ++e) o[e] = f2bf(Lt[kc + e][n]);
    *(u16x8*)(out + (size_t)(n0out + n) * 2048 + k0 + kc) = o;
  }
}

// wt[n][k] = [Wq|Wk|Wv][k][n]
__global__ __launch_bounds__(256) void k_wt_qkv(const float* __restrict__ Wq, const float* __restrict__ Wk,
                                                const float* __restrict__ Wv, u16* __restrict__ wt) {
  __shared__ float Lt[64][68];
  const int n0 = blockIdx.x * 64, k0 = blockIdx.y * 64;
  const float* src; int ldw, nb;
  if (n0 < 2048)      { src = Wq; ldw = 2048; nb = n0; }
  else if (n0 < 2560) { src = Wk; ldw = 512;  nb = n0 - 2048; }
  else                { src = Wv; ldw = 512;  nb = n0 - 2560; }
  ttile(src, ldw, nb, k0, n0, wt, threadIdx.x, Lt);
}

__global__ __launch_bounds__(256) void k_wo_t(const float* __restrict__ Wo, u16* __restrict__ wt) {
  __shared__ float Lt[64][68];
  ttile(Wo, 2048, blockIdx.x * 64, blockIdx.y * 64, blockIdx.x * 64, wt, threadIdx.x, Lt);
}

__global__ __launch_bounds__(256) void k_cs(float* __restrict__ cst) {
  int idx = blockIdx.x * 256 + threadIdx.x;   // 131072
  int t = idx >> 6, d = idx & 63;
  float inv = expf(-(float)d * (1.0f / 64.0f) * 9.2103403719761836f);
  float f = (float)t * inv;
  float s, c;
  sincosf(f, &s, &c);
  cst[idx * 2] = c;
  cst[idx * 2 + 1] = s;
}

// RoPE in place, x8 vectorized; folds 1/sqrt(HD) into q heads
__global__ __launch_bounds__(256) void k_rope(u16* __restrict__ qkv, const float* __restrict__ cst) {
  int idx = blockIdx.x * 256 + threadIdx.x;   // 1,310,720
  int token = idx / 160;
  int rem = idx - token * 160;
  int hd = rem >> 3, oct = rem & 7;
  int col = ((hd < 16) ? hd * 128 : 2048 + (hd - 16) * 128) + oct * 8;
  size_t base = (size_t)token * LDQKV + col;
  int t = token & (T_ - 1);
  float sc = (hd < 16) ? 0.08838834764831845f : 1.0f;
  u16x8 a = *(const u16x8*)(qkv + base);
  u16x8 b2 = *(const u16x8*)(qkv + base + 64);
  const float* cp = cst + (size_t)(t * 64 + oct * 8) * 2;
  u16x8 ra, rb;
#pragma unroll
  for (int e = 0; e < 8; ++e) {
    float c = cp[e * 2], s = cp[e * 2 + 1];
    float x1 = bf2f(a[e]), x2 = bf2f(b2[e]);
    ra[e] = f2bf((x1 * c - x2 * s) * sc);
    rb[e] = f2bf((x1 * s + x2 * c) * sc);
  }
  *(u16x8*)(qkv + base) = ra;
  *(u16x8*)(qkv + base + 64) = rb;
}

// ---------- 256x256 8-phase GEMM (T1+T2+T3+T4+T5): C[M][N] = A[M][K] * Bt[N][K]^T ----------
// 8 waves (2M x 4N), BK=64, dbuf LDS 128KB. Counted vmcnt(6), raw barriers, chunk-XOR swizzle.
// Staging schedule (race-free by region liveness):
//   tile t phases issue: ph0 -> (t+1):B1 [other buf]; ph1 -> (t+2):B0 [cur.B read done at ph0 close];
//   ph2 -> (t+2):A0, ph3 -> (t+2):A1 [all cur.A reads forced done by LGKM0 before ph1 close].
//   vmcnt(6) at ph3 drains tile t+1's 4 half-tiles, leaves 3 of t+2 in flight.
#define READ_A(mf, ks) (*(const bf16x8*)&As_[(wm * 128 + (mf) * 16 + l15) * 64 + ((((ks) * 4 + lhi) ^ (l15 & 7)) * 8)])
#define READ_B(nf, ks) (*(const bf16x8*)&Bs_[(wn * 64 + (nf) * 16 + l15) * 64 + ((((ks) * 4 + lhi) ^ (l15 & 7)) * 8)])
#define MFMA_QUAD(Q)                                                          \
  _Pragma("unroll") for (int mi = 0; mi < 2; ++mi)                            \
  _Pragma("unroll") for (int nf = 0; nf < 4; ++nf)                            \
  _Pragma("unroll") for (int ks = 0; ks < 2; ++ks)                            \
      acc[(Q) * 2 + mi][nf] = __builtin_amdgcn_mfma_f32_16x16x32_bf16(        \
          af[(Q) * 2 + mi][ks], bb[nf][ks], acc[(Q) * 2 + mi][nf], 0, 0, 0);

template<int OUTF32>
__global__ __launch_bounds__(512, 2) void k_gemm8(const u16* __restrict__ A, const u16* __restrict__ Bt,
                                                  void* __restrict__ Cout, int M, int N, int K, int nbx) {
  __shared__ __attribute__((aligned(16))) u16 lds[2][2][256 * 64];  // [buf][A/B][row*64+col]
  const int tid = threadIdx.x, lane = tid & 63;
  const int w = tid >> 6, wm = w >> 2, wn = w & 3;
  const int l15 = lane & 15, lhi = lane >> 4;
  // XCD-aware swizzle (grid % 8 == 0 for both GEMMs)
  const int nwg = gridDim.x, cpx = nwg >> 3;
  const int wg = (blockIdx.x & 7) * cpx + (blockIdx.x >> 3);
  const int bx = wg % nbx, by = wg / nbx;
  const int m0 = by * 256, n0 = bx * 256;
  const int NT = K >> 6;

  // stage half-tile: half 0=A0,1=A1,2=B0,3=B1 of K-tile tt -> buf[tt&1]
  auto STAGE = [&](int half, int tt) {
    const u16* src = (half < 2) ? A : Bt;
    const int r0 = ((half < 2) ? m0 : n0) + (half & 1) * 128;
    u16* dst = &lds[tt & 1][half >> 1][(half & 1) * 8192];
    const int kk = tt * 64;
#pragma unroll
    for (int it = 0; it < 2; ++it) {
      int c = it * 512 + tid;
      int row = c >> 3, kc = c & 7;
      gload_lds16(src + (size_t)(r0 + row) * K + kk + ((kc ^ (row & 7)) * 8), dst + c * 8);
    }
  };

  f32x4 acc[8][4];
#pragma unroll
  for (int i = 0; i < 8; ++i)
#pragma unroll
    for (int j = 0; j < 4; ++j) acc[i][j] = (f32x4){0.f, 0.f, 0.f, 0.f};

  // prologue: tile0 fully + 3 halves of tile1; drain tile0 (leave 6 loads = 3 halves)
  STAGE(0, 0); STAGE(1, 0); STAGE(2, 0); STAGE(3, 0);
  STAGE(0, 1); STAGE(1, 1); STAGE(2, 1);
  VMCNT(6);
  BAR();

  for (int t = 0; t < NT; ++t) {
    const u16* As_ = lds[t & 1][0];
    const u16* Bs_ = lds[t & 1][1];
    bf16x8 af[8][2], bb[4][2];
    // ---- phase 0: read B(8) + A-quad0(4); stage (t+1):B1
#pragma unroll
    for (int nf = 0; nf < 4; ++nf) { bb[nf][0] = READ_B(nf, 0); bb[nf][1] = READ_B(nf, 1); }
#pragma unroll
    for (int mf = 0; mf < 2; ++mf) { af[mf][0] = READ_A(mf, 0); af[mf][1] = READ_A(mf, 1); }
    if (t + 1 < NT) STAGE(3, t + 1);
    BAR();
    __builtin_amdgcn_s_setprio(1);
    MFMA_QUAD(0);
    __builtin_amdgcn_s_setprio(0);
    BAR();
    // ---- phase 1: read A-quads 1..3 (12); stage (t+2):B0
#pragma unroll
    for (int mf = 2; mf < 8; ++mf) { af[mf][0] = READ_A(mf, 0); af[mf][1] = READ_A(mf, 1); }
    if (t + 2 < NT) STAGE(2, t + 2);
    BAR();
    __builtin_amdgcn_s_setprio(1);
    MFMA_QUAD(1);
    __builtin_amdgcn_s_setprio(0);
    LGKM0();   // force ALL A reads complete before ph1 close (so t+2:A0/A1 staging is safe)
    BAR();
    // ---- phase 2: pure MFMA; stage (t+2):A0
    if (t + 2 < NT) STAGE(0, t + 2);
    BAR();
    __builtin_amdgcn_s_setprio(1);
    MFMA_QUAD(2);
    __builtin_amdgcn_s_setprio(0);
    BAR();
    // ---- phase 3: pure MFMA; stage (t+2):A1; counted vmcnt
    if (t + 2 < NT) STAGE(1, t + 2);
    BAR();
    __builtin_amdgcn_s_setprio(1);
    MFMA_QUAD(3);
    __builtin_amdgcn_s_setprio(0);
    if (t + 2 < NT) { VMCNT(6); } else { VMCNT(0); }
    BAR();
  }

  // epilogue: rows m0+wm*128+mf*16+lhi*4+r, cols n0+wn*64+nf*16+l15
#pragma unroll
  for (int mf = 0; mf < 8; ++mf) {
#pragma unroll
    for (int nf = 0; nf < 4; ++nf) {
      int col = n0 + wn * 64 + nf * 16 + l15;
#pragma unroll
      for (int r = 0; r < 4; ++r) {
        int row = m0 + wm * 128 + mf * 16 + lhi * 4 + r;
        float v = acc[mf][nf][r];
        if (OUTF32) ((float*)Cout)[(size_t)row * N + col] = v;
        else        ((u16*)Cout)[(size_t)row * N + col] = f2bf(v);
      }
    }
  }
}

// ---------- windowed flash attention (swizzled, conflict-free; unchanged from R2) ----------
__global__ __launch_bounds__(256) void k_attn(const u16* __restrict__ qkv, u16* __restrict__ y) {
  const int bid = blockIdx.x;
  const int qt = bid & 31, h = (bid >> 5) & 15, b = bid >> 9;
  const int i0 = qt * 64;
  const size_t tb = (size_t)b * T_ * LDQKV;
  const u16* qb = qkv + tb + h * HD;
  const u16* kb = qkv + tb + 2048 + (h >> 2) * HD;
  const u16* vb = kb + 512;
  __shared__ __attribute__((aligned(16))) u16 smem[20480];   // 40 KB
  u16* Ks = smem;
  u16* Vt = smem + 8192;
  u16* Psw = smem + 16384;
  u16* Qs = smem;
  const int tid = threadIdx.x, lane = tid & 63, w = tid >> 6;
  const int l15 = lane & 15, lhi = lane >> 4;
  u16* Ps = Psw + w * 1024;

#pragma unroll
  for (int it = 0; it < 4; ++it) {
    int c = it * 256 + tid, row = c >> 4, kc = (c & 15) ^ (row & 7);
    gload_lds16(qb + (size_t)(i0 + row) * LDQKV + kc * 8, &Qs[(it * 256 + w * 64) * 8]);
  }
  __syncthreads();
  bf16x8 qf[4];
#pragma unroll
  for (int ks = 0; ks < 4; ++ks) {
    int row = w * 16 + l15;
    int kc = (ks * 4 + lhi) ^ (row & 7);
    qf[ks] = *(const bf16x8*)&Qs[(row * 16 + kc) * 8];
  }
  __syncthreads();

  f32x4 o[8];
#pragma unroll
  for (int dt = 0; dt < 8; ++dt) o[dt] = (f32x4){0.f, 0.f, 0.f, 0.f};
  float mrun[4], lrun[4];
#pragma unroll
  for (int r = 0; r < 4; ++r) { mrun[r] = -1e30f; lrun[r] = 0.f; }

  const int jb0 = (i0 >= 256) ? (i0 - 256) : 0;
  for (int jb = jb0; jb <= i0; jb += 64) {
#pragma unroll
    for (int it = 0; it < 4; ++it) {
      int c = it * 256 + tid, row = c >> 4, kc = (c & 15) ^ (row & 7);
      gload_lds16(kb + (size_t)(jb + row) * LDQKV + kc * 8, &Ks[(it * 256 + w * 64) * 8]);
    }
#pragma unroll
    for (int it = 0; it < 4; ++it) {
      int chunk = it * 256 + tid, row = chunk >> 4, dc = chunk & 15;
      u16x8 vv = *(const u16x8*)(vb + (size_t)(jb + row) * LDQKV + dc * 8);
#pragma unroll
      for (int e = 0; e < 8; ++e) {
        int d = dc * 8 + e;
        int s = (dc ^ e) & 7;
        Vt[d * 64 + (row ^ (s << 3))] = vv[e];
      }
    }
    __syncthreads();

    f32x4 s[4];
#pragma unroll
    for (int t = 0; t < 4; ++t) {
      s[t] = (f32x4){0.f, 0.f, 0.f, 0.f};
#pragma unroll
      for (int ks = 0; ks < 4; ++ks) {
        int row = t * 16 + l15;
        int kc = (ks * 4 + lhi) ^ (row & 7);
        bf16x8 kf = *(const bf16x8*)&Ks[(row * 16 + kc) * 8];
        s[t] = __builtin_amdgcn_mfma_f32_16x16x32_bf16(qf[ks], kf, s[t], 0, 0, 0);
      }
    }

    const int irow0 = i0 + w * 16 + lhi * 4;
    float rmax[4];
#pragma unroll
    for (int r = 0; r < 4; ++r) rmax[r] = -1e30f;
#pragma unroll
    for (int t = 0; t < 4; ++t) {
      int j = jb + t * 16 + l15;
#pragma unroll
      for (int r = 0; r < 4; ++r) {
        int i = irow0 + r;
        float sv = s[t][r];
        sv = (j <= i && j + 256 >= i) ? sv : -1e30f;
        s[t][r] = sv;
        rmax[r] = fmaxf(rmax[r], sv);
      }
    }
#pragma unroll
    for (int r = 0; r < 4; ++r) {
#pragma unroll
      for (int off = 1; off < 16; off <<= 1)
        rmax[r] = fmaxf(rmax[r], __shfl_xor(rmax[r], off));
    }
    float sf[4], psum[4];
#pragma unroll
    for (int r = 0; r < 4; ++r) {
      float mn = fmaxf(mrun[r], rmax[r]);
      sf[r] = __expf(mrun[r] - mn);
      mrun[r] = mn;
      psum[r] = 0.f;
    }
#pragma unroll
    for (int t = 0; t < 4; ++t) {
#pragma unroll
      for (int r = 0; r < 4; ++r) {
        float p = __expf(s[t][r] - mrun[r]);
        psum[r] += p;
        int q = lhi * 4 + r;
        int k = t * 16 + l15;
        Ps[q * 64 + (k ^ ((q & 7) << 3))] = f2bf(p);
      }
    }
#pragma unroll
    for (int r = 0; r < 4; ++r) {
#pragma unroll
      for (int off = 1; off < 16; off <<= 1)
        psum[r] += __shfl_xor(psum[r], off);
      lrun[r] = lrun[r] * sf[r] + psum[r];
    }
#pragma unroll
    for (int dt = 0; dt < 8; ++dt)
#pragma unroll
      for (int r = 0; r < 4; ++r)
        o[dt][r] = o[dt][r] * sf[r];

    bf16x8 pf[2];
#pragma unroll
    for (int ks2 = 0; ks2 < 2; ++ks2)
      pf[ks2] = *(const bf16x8*)&Ps[l15 * 64 + ((ks2 * 32 + lhi * 8) ^ ((l15 & 7) << 3))];
#pragma unroll
    for (int dt = 0; dt < 8; ++dt) {
#pragma unroll
      for (int ks2 = 0; ks2 < 2; ++ks2) {
        int d = dt * 16 + l15;
        int s2 = ((d >> 3) ^ (d & 7)) & 7;
        bf16x8 vf = *(const bf16x8*)&Vt[d * 64 + ((ks2 * 32 + lhi * 8) ^ (s2 << 3))];
        o[dt] = __builtin_amdgcn_mfma_f32_16x16x32_bf16(pf[ks2], vf, o[dt], 0, 0, 0);
      }
    }
    __syncthreads();
  }

#pragma unroll
  for (int dt = 0; dt < 8; ++dt) {
#pragma unroll
    for (int r = 0; r < 4; ++r) {
      int i = i0 + w * 16 + lhi * 4 + r;
      float v = o[dt][r] / lrun[r];
      y[((size_t)b * T_ + i) * C_ + h * HD + dt * 16 + l15] = f2bf(v);
    }
  }
}

extern "C" void kernel_launch(void* const* d_in, const int* in_sizes, int n_in,
                              void* d_out, int out_size, void* d_ws, size_t ws_size,
                              hipStream_t stream) {
  const float* x  = (const float*)d_in[0];
  const float* Wq = (const float*)d_in[1];
  const float* Wk = (const float*)d_in[2];
  const float* Wv = (const float*)d_in[3];
  const float* Wo = (const float*)d_in[4];
  char* ws = (char*)d_ws;
  u16* x_bf   = (u16*)(ws);                 // 33,554,432 B (reused as y after GEMM1)
  u16* wt_qkv = (u16*)(ws + 33554432);      // 12,582,912 B
  u16* wo_t   = (u16*)(ws + 46137344);      //  8,388,608 B
  u16* qkv    = (u16*)(ws + 54525952);      // 50,331,648 B
  float* cst  = (float*)(ws + 104857600);   //  1,048,576 B
  u16* ybuf = x_bf;

  k_conv_x <<<16384, 256, 0, stream>>>(x, x_bf);
  k_wt_qkv <<<dim3(48, 32), 256, 0, stream>>>(Wq, Wk, Wv, wt_qkv);
  k_wo_t   <<<dim3(32, 32), 256, 0, stream>>>(Wo, wo_t);
  k_cs     <<<512, 256, 0, stream>>>(cst);

  k_gemm8<0><<<384, 512, 0, stream>>>(x_bf, wt_qkv, (void*)qkv, 8192, 3072, 2048, 12);

  k_rope   <<<5120, 256, 0, stream>>>(qkv, cst);
  k_attn   <<<2048, 256, 0, stream>>>(qkv, ybuf);

  k_gemm8<1><<<256, 512, 0, stream>>>(ybuf, wo_t, d_out, 8192, 2048, 2048, 8);
}